// Round 6
// baseline (259.866 us; speedup 1.0000x reference)
//
#include <hip/hip_runtime.h>
#include <hip/hip_fp16.h>
#include <cstddef>
#include <cstdint>

// Problem constants (fixed by reference setup_inputs)
#define DMODEL 256
#define NHEAD  8
#define NLVL   4
#define NPT    4
#define DHEAD  32
#define DFFN   1024
#define SLEN   5440
#define BATCH  4
#define NTOK   (BATCH * SLEN)   // 21760 = 340*64 = 170*128
#define NT256  ((size_t)NTOK * 256)
#define GYR    170              // row-panels of 128 rows
#define GYP    176              // padded to multiple of 8 for XCD swizzle
#define LN_EPS 1e-5f

typedef __attribute__((ext_vector_type(4))) float f32x4;
typedef __attribute__((ext_vector_type(8))) short s16x8;

__device__ __forceinline__ unsigned short f2bf(float f) {
    union { float f; unsigned u; } v; v.f = f;
    unsigned u = v.u;
    u += 0x7FFFu + ((u >> 16) & 1u);   // round-to-nearest-even
    return (unsigned short)(u >> 16);
}
__device__ __forceinline__ float bf2f(unsigned short h) {
    union { unsigned u; float f; } v; v.u = ((unsigned)h) << 16;
    return v.f;
}

// async 16B global -> LDS (direct-to-shared, no VGPR round trip).
// lds dest must be wave-uniform base; HW writes lane l at base + l*16B.
__device__ __forceinline__ void g2l16(const unsigned short* g, unsigned short* l) {
    __builtin_amdgcn_global_load_lds(
        (const __attribute__((address_space(1))) unsigned int*)g,
        (__attribute__((address_space(3))) unsigned int*)l, 16, 0, 0);
}

// ---------------------------------------------------------------------------
// Fused prep + weight transposes (one launch).
// Blocks [0, 5440):   srcB = bf16(src); qB = bf16(src + pos)
// Blocks [5440, 5624): W [K][N] fp32 -> Wt [N][K] bf16 (all 6 weights;
//                      Woff & Wa into ONE concatenated WcatT [384][256]).
// ---------------------------------------------------------------------------
__global__ __launch_bounds__(256) void prep_tr_kernel(
    const float* __restrict__ src, const float* __restrict__ pos,
    unsigned short* __restrict__ srcB, unsigned short* __restrict__ qB,
    const float* __restrict__ Wv, const float* __restrict__ Woff,
    const float* __restrict__ Wa, const float* __restrict__ Wo,
    const float* __restrict__ W1, const float* __restrict__ W2,
    unsigned short* __restrict__ WvT, unsigned short* __restrict__ WcatT,
    unsigned short* __restrict__ WoT,
    unsigned short* __restrict__ W1T, unsigned short* __restrict__ W2T)
{
    if (blockIdx.x < 5440) {
        const size_t i = ((size_t)blockIdx.x * 256 + threadIdx.x) * 4;
        const float4 s = *(const float4*)(src + i);
        const float4 p = *(const float4*)(pos + i);
        ushort4 sb, qb;
        sb.x = f2bf(s.x); sb.y = f2bf(s.y); sb.z = f2bf(s.z); sb.w = f2bf(s.w);
        qb.x = f2bf(s.x + p.x); qb.y = f2bf(s.y + p.y);
        qb.z = f2bf(s.z + p.z); qb.w = f2bf(s.w + p.w);
        *(ushort4*)(srcB + i) = sb;
        *(ushort4*)(qB + i) = qb;
        return;
    }
    const int bid = blockIdx.x - 5440;
    const float* W; unsigned short* Wt; int K, N, t;
    if (bid < 16)       { W = Wv;   Wt = WvT;              K = 256;  N = 256;  t = bid; }
    else if (bid < 32)  { W = Woff; Wt = WcatT;            K = 256;  N = 256;  t = bid - 16; }
    else if (bid < 40)  { W = Wa;   Wt = WcatT + 256*256;  K = 256;  N = 128;  t = bid - 32; }
    else if (bid < 56)  { W = Wo;   Wt = WoT;              K = 256;  N = 256;  t = bid - 40; }
    else if (bid < 120) { W = W1;   Wt = W1T;              K = 256;  N = 1024; t = bid - 56; }
    else                { W = W2;   Wt = W2T;              K = 1024; N = 256;  t = bid - 120; }
    const int ntx = N >> 6;
    const int k0 = (t / ntx) * 64, n0 = (t % ntx) * 64;

    __shared__ float T[64][65];
    const int r  = threadIdx.x >> 4;
    const int c4 = (threadIdx.x & 15) * 4;
    #pragma unroll
    for (int rep = 0; rep < 4; rep++) {
        const int k = rep * 16 + r;
        const float4 v = *(const float4*)(W + (size_t)(k0 + k) * N + n0 + c4);
        T[c4 + 0][k] = v.x; T[c4 + 1][k] = v.y;
        T[c4 + 2][k] = v.z; T[c4 + 3][k] = v.w;
    }
    __syncthreads();
    #pragma unroll
    for (int rep = 0; rep < 4; rep++) {
        const int n = rep * 16 + r;
        ushort4 o;
        o.x = f2bf(T[n][c4 + 0]); o.y = f2bf(T[n][c4 + 1]);
        o.z = f2bf(T[n][c4 + 2]); o.w = f2bf(T[n][c4 + 3]);
        *(ushort4*)(Wt + (size_t)(n0 + n) * K + k0 + c4) = o;
    }
}

// ---------------------------------------------------------------------------
// WIDE full-N GEMM for N<=384: BM=128, BN=N, 4 waves (2x2, wave tile
// 64 x BN/2), double-buffered async-LDS staging with counted vmcnt.
// Rationale (round-5 diagnosis): the 128x128 kernel at 2 blocks/CU is
// LDS-read-BW bound (128KB/CU per K-step) AND grid=340 leaves 84 CUs with
// 2 blocks (2x imbalance). This kernel: 48KB/CU per K-step (wave reads
// 4 A + BN/32 B frags feeding 4*(BN/32) MFMAs = 25% less LDS per FLOP),
// 1 block/CU, grid = exactly 170 = one balanced shift.
// LDS XOR-swizzle as before (pre-swizzled global source + swizzled read).
// Per K-step: vmcnt(12|16) [tile kt+1 stays in flight] -> barrier ->
// compute -> lgkmcnt(0) -> barrier -> stage kt+2. No vmcnt(0) in the loop.
// Bias split at bsplit. OM: 0=f32, 1=bf16, 2=f16.
// ---------------------------------------------------------------------------
template <int KK, int BN, bool RELU, int OM>
__global__ __launch_bounds__(256, 1) void gemm_wide_kernel(
    const unsigned short* __restrict__ A,
    const unsigned short* __restrict__ Bt,
    const float* __restrict__ bias, const float* __restrict__ bias2,
    int bsplit,
    void* __restrict__ Cout)
{
    const int row0 = blockIdx.x * 128;

    __shared__ __align__(16) unsigned short sA[2][128 * 64];
    __shared__ __align__(16) unsigned short sB[2][BN * 64];

    const int tid  = threadIdx.x;
    const int wid  = tid >> 6;
    const int lane = tid & 63;
    const int m16  = lane & 15;
    const int q    = lane >> 4;
    const int wr   = (wid >> 1) * 64;        // wave's output row half
    const int wc   = (wid & 1) * (BN / 2);   // wave's output col half

    // staging: instr j covers LDS rows j*8..j*8+7 (1KB). lane l -> row
    // j*8 + (l>>3), global 16B-chunk (l&7)^(l>>3) (pre-swizzle).
    const int srow = lane >> 3;
    const int schk = (lane & 7) ^ srow;

    constexpr int AI = 4;            // A stage instrs per wave (16 rows*8 /4w)
    constexpr int BI = BN / 32;      // B stage instrs per wave
    constexpr int NF = BN / 32;      // n-frags per wave (BN/2 cols / 16)

    auto stage = [&](int buf, int kt) {      // AI+BI vmcnt ops per wave
        #pragma unroll
        for (int i = 0; i < AI; i++) {
            const int j = wid * AI + i;      // 0..15
            const int r = j * 8 + srow;
            g2l16(A + (size_t)(row0 + r) * KK + kt * 64 + schk * 8,
                  &sA[buf][j * 512]);
        }
        #pragma unroll
        for (int i = 0; i < BI; i++) {
            const int j = wid * BI + i;      // 0..BN/8-1
            const int r = j * 8 + srow;      // global B row (= output col)
            g2l16(Bt + (size_t)r * KK + kt * 64 + schk * 8,
                  &sB[buf][j * 512]);
        }
    };

    f32x4 acc[4][NF];
    #pragma unroll
    for (int m = 0; m < 4; m++)
        #pragma unroll
        for (int n = 0; n < NF; n++) acc[m][n] = (f32x4){0.f, 0.f, 0.f, 0.f};

    constexpr int NT = KK / 64;              // >= 4 for all instantiations
    stage(0, 0);
    stage(1, 1);                             // 2*(AI+BI) loads in flight

    #pragma unroll 1
    for (int kt = 0; kt < NT; kt++) {
        const int cur = kt & 1;

        // tile kt's loads (oldest) done; kt+1's stay in flight
        if (kt + 1 < NT) {
            if constexpr (BN == 256) asm volatile("s_waitcnt vmcnt(12)" ::: "memory");
            else                     asm volatile("s_waitcnt vmcnt(16)" ::: "memory");
        } else {
            asm volatile("s_waitcnt vmcnt(0)" ::: "memory");
        }
        __builtin_amdgcn_sched_barrier(0);
        __builtin_amdgcn_s_barrier();        // all waves' tile-kt loads done
        __builtin_amdgcn_sched_barrier(0);

        #pragma unroll
        for (int ks = 0; ks < 2; ks++) {
            s16x8 a[4], b[NF];
            #pragma unroll
            for (int m = 0; m < 4; m++) {
                const int r  = wr + m * 16 + m16;
                const int cc = (ks * 4 + q) ^ (r & 7);   // un-swizzle on read
                a[m] = *(const s16x8*)&sA[cur][r * 64 + cc * 8];
            }
            #pragma unroll
            for (int n = 0; n < NF; n++) {
                const int r  = wc + n * 16 + m16;
                const int cc = (ks * 4 + q) ^ (r & 7);
                b[n] = *(const s16x8*)&sB[cur][r * 64 + cc * 8];
            }
            #pragma unroll
            for (int m = 0; m < 4; m++)
                #pragma unroll
                for (int n = 0; n < NF; n++)
                    acc[m][n] = __builtin_amdgcn_mfma_f32_16x16x32_bf16(
                        a[m], b[n], acc[m][n], 0, 0, 0);
        }

        // my ds_reads of buf cur complete -> barrier -> safe to overwrite
        asm volatile("s_waitcnt lgkmcnt(0)" ::: "memory");
        __builtin_amdgcn_sched_barrier(0);
        __builtin_amdgcn_s_barrier();
        __builtin_amdgcn_sched_barrier(0);

        if (kt + 2 < NT) stage(cur, kt + 2);   // same parity: kt+2 -> buf cur
    }

    // epilogue: D layout col=lane&15, row=(lane>>4)*4+reg (m89/m91-verified)
    #pragma unroll
    for (int n = 0; n < NF; n++) {
        const int col  = wc + n * 16 + m16;
        const float bc = (col < bsplit) ? bias[col] : bias2[col - bsplit];
        #pragma unroll
        for (int m = 0; m < 4; m++) {
            #pragma unroll
            for (int r = 0; r < 4; r++) {
                const int row = row0 + wr + m * 16 + q * 4 + r;
                float v = acc[m][n][r] + bc;
                if (RELU) v = fmaxf(v, 0.f);
                if (OM == 1)
                    ((unsigned short*)Cout)[(size_t)row * BN + col] = f2bf(v);
                else if (OM == 2)
                    ((__half*)Cout)[(size_t)row * BN + col] = __float2half(v);
                else
                    ((float*)Cout)[(size_t)row * BN + col] = v;
            }
        }
    }
}

// ---------------------------------------------------------------------------
// 128x128 async-LDS GEMM with counted-vmcnt pipeline (round-5 validated).
// Kept for FFN1 (N=1024, NXB=8). Structure unchanged.
// ---------------------------------------------------------------------------
template <int KK, int NXB, bool RELU, int OM>
__global__ __launch_bounds__(256, 2) void gemm_lds_kernel(
    const unsigned short* __restrict__ A,
    const unsigned short* __restrict__ Bt,
    const float* __restrict__ bias, const float* __restrict__ bias2,
    int bsplit,
    void* __restrict__ Cout, int N)
{
    const int lin = blockIdx.x;
    const int c8  = lin & 7;
    const int rr  = lin >> 3;
    const int bx  = rr % NXB;
    const int yy  = (rr / NXB) * 8 + c8;
    if (yy >= GYR) return;              // uniform per block: safe before barrier
    const int row0 = yy * 128;
    const int col0 = bx * 128;

    __shared__ __align__(16) unsigned short sA[2][128 * 64];
    __shared__ __align__(16) unsigned short sB[2][128 * 64];

    const int tid  = threadIdx.x;
    const int wid  = tid >> 6;
    const int lane = tid & 63;
    const int m16  = lane & 15;
    const int q    = lane >> 4;
    const int wr   = (wid >> 1) * 64;    // wave's output row half
    const int wc   = (wid & 1) * 64;     // wave's output col half

    const int srow = lane >> 3;
    const int schk = (lane & 7) ^ srow;

    auto stage = [&](int buf, int kt) {   // 8 vmcnt ops per wave
        #pragma unroll
        for (int i = 0; i < 4; i++) {
            const int j = wid * 4 + i;           // 0..15 across the 4 waves
            const int r = j * 8 + srow;
            g2l16(A  + (size_t)(row0 + r) * KK + kt * 64 + schk * 8,
                  &sA[buf][j * 512]);
            g2l16(Bt + (size_t)(col0 + r) * KK + kt * 64 + schk * 8,
                  &sB[buf][j * 512]);
        }
    };

    f32x4 acc[4][4];
    #pragma unroll
    for (int m = 0; m < 4; m++)
        #pragma unroll
        for (int n = 0; n < 4; n++) acc[m][n] = (f32x4){0.f, 0.f, 0.f, 0.f};

    constexpr int NT = KK / 64;
    stage(0, 0);
    stage(1, 1);                         // 16 loads in flight

    #pragma unroll 1
    for (int kt = 0; kt < NT; kt++) {
        const int cur = kt & 1;

        if (kt + 1 < NT) asm volatile("s_waitcnt vmcnt(8)" ::: "memory");
        else             asm volatile("s_waitcnt vmcnt(0)" ::: "memory");
        __builtin_amdgcn_sched_barrier(0);
        __builtin_amdgcn_s_barrier();    // all waves' tile-kt loads done
        __builtin_amdgcn_sched_barrier(0);

        #pragma unroll
        for (int ks = 0; ks < 2; ks++) {
            s16x8 a[4], b[4];
            #pragma unroll
            for (int m = 0; m < 4; m++) {
                const int r  = wr + m * 16 + m16;
                const int cc = (ks * 4 + q) ^ (r & 7);   // un-swizzle on read
                a[m] = *(const s16x8*)&sA[cur][r * 64 + cc * 8];
            }
            #pragma unroll
            for (int n = 0; n < 4; n++) {
                const int r  = wc + n * 16 + m16;
                const int cc = (ks * 4 + q) ^ (r & 7);
                b[n] = *(const s16x8*)&sB[cur][r * 64 + cc * 8];
            }
            #pragma unroll
            for (int m = 0; m < 4; m++)
                #pragma unroll
                for (int n = 0; n < 4; n++)
                    acc[m][n] = __builtin_amdgcn_mfma_f32_16x16x32_bf16(
                        a[m], b[n], acc[m][n], 0, 0, 0);
        }

        asm volatile("s_waitcnt lgkmcnt(0)" ::: "memory");
        __builtin_amdgcn_sched_barrier(0);
        __builtin_amdgcn_s_barrier();
        __builtin_amdgcn_sched_barrier(0);

        if (kt + 2 < NT) stage(cur, kt + 2);   // same parity: kt+2 -> buf cur
    }

    #pragma unroll
    for (int n = 0; n < 4; n++) {
        const int col  = col0 + wc + n * 16 + m16;
        const float bc = (col < bsplit) ? bias[col] : bias2[col - bsplit];
        #pragma unroll
        for (int m = 0; m < 4; m++) {
            #pragma unroll
            for (int r = 0; r < 4; r++) {
                const int row = row0 + wr + m * 16 + q * 4 + r;
                float v = acc[m][n][r] + bc;
                if (RELU) v = fmaxf(v, 0.f);
                if (OM == 1)
                    ((unsigned short*)Cout)[(size_t)row * N + col] = f2bf(v);
                else if (OM == 2)
                    ((__half*)Cout)[(size_t)row * N + col] = __float2half(v);
                else
                    ((float*)Cout)[(size_t)row * N + col] = v;
            }
        }
    }
}

// ---------------------------------------------------------------------------
// MSDA fused meta+gather: block = 8 tokens.
// Phase 1 (meta): tid -> (tok=tid>>5, h=(tid>>2)&7, pg=tid&3). Each thread
//   owns the 4 points of level pg for (tok,h): softmax over the 16 points is
//   a 4-lane shfl_xor group reduce. Packed idx+weights in a 16KB LDS table.
// Phase 2 (gather): validated sampler, meta read from LDS.
// XCD swizzle: batch b's 680 blocks -> XCD pair {2b, 2b+1} so each batch's
// 2.78 MB value plane is L2-resident.
// ---------------------------------------------------------------------------
__global__ __launch_bounds__(256) void msda_sample_kernel(
    const __half* __restrict__ value, const float* __restrict__ olg,
    unsigned short* __restrict__ out)
{
    const int lin = blockIdx.x;          // 0..2719
    const int c8  = lin & 7;
    const int rr  = lin >> 3;            // 0..339
    const int b   = c8 >> 1;             // batch -> XCD pair
    const int i8  = (c8 & 1) + 2 * rr;   // 0..679: block within batch

    const int tid = threadIdx.x;
    const int sub = tid & 3;             // phase2: 16B channel group; phase1: pg
    const int h   = (tid >> 2) & 7;
    const int t8  = tid >> 5;
    const int q   = i8 * 8 + t8;         // token index within batch (< SLEN)
    const int bq  = b * SLEN + q;

    __shared__ __align__(16) uint4 smeta[8 * 16 * 8];   // [tok][p][h], 16KB

    // ---------------- phase 1: meta for (tok=t8, h, level=sub) -------------
    {
        int rem, Wq;
        if (q < 4096)      { rem = q;        Wq = 64; }
        else if (q < 5120) { rem = q - 4096; Wq = 32; }
        else if (q < 5376) { rem = q - 5120; Wq = 16; }
        else               { rem = q - 5376; Wq = 8;  }
        const int gy = rem / Wq;
        const int gx = rem - gy * Wq;
        const float ref_x = (gx + 0.5f) / (float)Wq;
        const float ref_y = (gy + 0.5f) / (float)Wq;

        const float4 lgv = *(const float4*)(olg + (size_t)bq * 384 + 256 + h * 16 + sub * 4);
        float mx = fmaxf(fmaxf(lgv.x, lgv.y), fmaxf(lgv.z, lgv.w));
        mx = fmaxf(mx, __shfl_xor(mx, 1));
        mx = fmaxf(mx, __shfl_xor(mx, 2));
        float e0 = expf(lgv.x - mx), e1 = expf(lgv.y - mx);
        float e2 = expf(lgv.z - mx), e3 = expf(lgv.w - mx);
        float s = e0 + e1 + e2 + e3;
        s += __shfl_xor(s, 1);
        s += __shfl_xor(s, 2);
        const float inv_s = 1.f / s;

        const float4 o01 = *(const float4*)(olg + (size_t)bq * 384 + h * 32 + sub * 8);
        const float4 o23 = *(const float4*)(olg + (size_t)bq * 384 + h * 32 + sub * 8 + 4);

        constexpr int LW[4] = {64, 32, 16, 8};
        constexpr int LS[4] = {0, 4096, 5120, 5376};
        const int Wl = LW[sub];
        const float fW = (float)Wl;
        const float ew[4] = {e0, e1, e2, e3};
        const float ox[4] = {o01.x, o01.z, o23.x, o23.z};
        const float oy[4] = {o01.y, o01.w, o23.y, o23.w};

        #pragma unroll
        for (int j = 0; j < 4; j++) {
            const float aw = ew[j] * inv_s;
            // mirror reference arithmetic exactly: (ref + off/W)*W - 0.5
            const float X = (ref_x + ox[j] / fW) * fW - 0.5f;
            const float Y = (ref_y + oy[j] / fW) * fW - 0.5f;
            const float x0f = floorf(X), y0f = floorf(Y);
            const float fx = X - x0f, fy = Y - y0f;
            const int x0 = (int)x0f, y0 = (int)y0f;

            unsigned idx[4]; __half hw[4];
            #pragma unroll
            for (int dy = 0; dy < 2; dy++) {
                const int yi = y0 + dy;
                const float wy = dy ? fy : (1.f - fy);
                const bool vy = (yi >= 0) && (yi < Wl);
                const int yc = min(max(yi, 0), Wl - 1);
                #pragma unroll
                for (int dx = 0; dx < 2; dx++) {
                    const int xi = x0 + dx;
                    const float wx = dx ? fx : (1.f - fx);
                    const bool vx = (xi >= 0) && (xi < Wl);
                    const int xc = min(max(xi, 0), Wl - 1);
                    const int c = dy * 2 + dx;
                    idx[c] = (unsigned)(LS[sub] + yc * Wl + xc);   // < 5440
                    hw[c] = __float2half((vx && vy) ? (aw * wx * wy) : 0.f);
                }
            }
            union { __half2 h2; unsigned u; } pk0, pk1;
            pk0.h2 = __halves2half2(hw[0], hw[1]);
            pk1.h2 = __halves2half2(hw[2], hw[3]);
            uint4 m;
            m.x = idx[0] | (idx[1] << 16);
            m.y = idx[2] | (idx[3] << 16);
            m.z = pk0.u;
            m.w = pk1.u;
            smeta[((t8 * 16) + sub * 4 + j) * 8 + h] = m;
        }
    }
    __syncthreads();

    // ---------------- phase 2: gather (validated structure) ----------------
    const char* vb = (const char*)value + (size_t)b * SLEN * 512;
    const unsigned laneoff = (unsigned)(h * 64 + sub * 16);
    const uint4* metap = &smeta[(t8 * 16) * 8 + h];    // index with p*8

    __half2 acc[4][4];
    #pragma unroll
    for (int i = 0; i < 4; i++)
        #pragma unroll
        for (int k = 0; k < 4; k++)
            acc[i][k] = __float2half2_rn(0.f);

    for (int g = 0; g < 4; g++) {
        #pragma unroll
        for (int pp = 0; pp < 4; pp++) {
            const int p = g * 4 + pp;
            const uint4 m = metap[p * 8];
            const unsigned a0 = ((m.x & 0xFFFFu) << 9) + laneoff;
            const unsigned a1 = ((m.x >> 16) << 9) + laneoff;
            const unsigned a2 = ((m.y & 0xFFFFu) << 9) + laneoff;
            const unsigned a3 = ((m.y >> 16) << 9) + laneoff;
            const int4 v0 = *(const int4*)(vb + a0);
            const int4 v1 = *(const int4*)(vb + a1);
            const int4 v2 = *(const int4*)(vb + a2);
            const int4 v3 = *(const int4*)(vb + a3);
            union { unsigned u; __half2 h2; } wz, ww;
            wz.u = m.z; ww.u = m.w;
            const __half2 ws0 = __half2half2(__low2half(wz.h2));
            const __half2 ws1 = __half2half2(__high2half(wz.h2));
            const __half2 ws2 = __half2half2(__low2half(ww.h2));
            const __half2 ws3 = __half2half2(__high2half(ww.h2));
            const __half2* p0 = (const __half2*)&v0;
            const __half2* p1 = (const __half2*)&v1;
            const __half2* p2 = (const __half2*)&v2;
            const __half2* p3 = (const __half2*)&v3;
            #pragma unroll
            for (int k = 0; k < 4; k++) {
                acc[pp][k] = __hfma2(ws0, p0[k], acc[pp][k]);
                acc[pp][k] = __hfma2(ws1, p1[k], acc[pp][k]);
                acc[pp][k] = __hfma2(ws2, p2[k], acc[pp][k]);
                acc[pp][k] = __hfma2(ws3, p3[k], acc[pp][k]);
            }
        }
    }

    uint4 o;
    unsigned* ou = &o.x;
    #pragma unroll
    for (int k = 0; k < 4; k++) {
        float2 s = {0.f, 0.f};
        #pragma unroll
        for (int i = 0; i < 4; i++) {
            const float2 f = __half22float2(acc[i][k]);
            s.x += f.x; s.y += f.y;
        }
        ou[k] = (unsigned)f2bf(s.x) | ((unsigned)f2bf(s.y) << 16);
    }
    *(uint4*)(out + (size_t)bq * 256 + h * 32 + sub * 8) = o;
}

// ---------------------------------------------------------------------------
// Fused residual-add + LayerNorm. One wave per row, 4 rows/block.
// X1B/X2B: inputs bf16 (else fp32). WF: write fp32 out. WB: write bf16 out.
// ---------------------------------------------------------------------------
template <bool X1B, bool X2B, bool WF, bool WB>
__global__ __launch_bounds__(256) void ln_kernel(
    const void* __restrict__ x1, const void* __restrict__ x2,
    const float* __restrict__ g, const float* __restrict__ be,
    float* __restrict__ outf, unsigned short* __restrict__ outb)
{
    const int lane = threadIdx.x & 63;
    const int wid  = threadIdx.x >> 6;
    const size_t row  = (size_t)blockIdx.x * 4 + wid;
    const size_t base = row * 256 + lane * 4;

    float a0, a1, a2, a3, b0, b1, b2, b3;
    if (X1B) {
        const ushort4 a = *(const ushort4*)((const unsigned short*)x1 + base);
        a0 = bf2f(a.x); a1 = bf2f(a.y); a2 = bf2f(a.z); a3 = bf2f(a.w);
    } else {
        const float4 a = *(const float4*)((const float*)x1 + base);
        a0 = a.x; a1 = a.y; a2 = a.z; a3 = a.w;
    }
    if (X2B) {
        const ushort4 b = *(const ushort4*)((const unsigned short*)x2 + base);
        b0 = bf2f(b.x); b1 = bf2f(b.y); b2 = bf2f(b.z); b3 = bf2f(b.w);
    } else {
        const float4 b = *(const float4*)((const float*)x2 + base);
        b0 = b.x; b1 = b.y; b2 = b.z; b3 = b.w;
    }
    const float v0 = a0 + b0, v1 = a1 + b1, v2 = a2 + b2, v3 = a3 + b3;

    float s  = v0 + v1 + v2 + v3;
    float s2 = v0 * v0 + v1 * v1 + v2 * v2 + v3 * v3;
    #pragma unroll
    for (int o = 32; o > 0; o >>= 1) {
        s  += __shfl_xor(s, o);
        s2 += __shfl_xor(s2, o);
    }
    const float mu  = s * (1.f / 256.f);
    const float var = s2 * (1.f / 256.f) - mu * mu;
    const float r   = rsqrtf(var + LN_EPS);

    const float4 gv = *(const float4*)(g  + lane * 4);
    const float4 bv = *(const float4*)(be + lane * 4);
    float4 o4;
    o4.x = (v0 - mu) * r * gv.x + bv.x;
    o4.y = (v1 - mu) * r * gv.y + bv.y;
    o4.z = (v2 - mu) * r * gv.z + bv.z;
    o4.w = (v3 - mu) * r * gv.w + bv.w;
    if (WF) *(float4*)(outf + base) = o4;
    if (WB) {
        ushort4 ob;
        ob.x = f2bf(o4.x); ob.y = f2bf(o4.y); ob.z = f2bf(o4.z); ob.w = f2bf(o4.w);
        *(ushort4*)(outb + base) = ob;
    }
}

// ---------------------------------------------------------------------------
extern "C" void kernel_launch(void* const* d_in, const int* in_sizes, int n_in,
                              void* d_out, int out_size, void* d_ws, size_t ws_size,
                              hipStream_t stream)
{
    const float* src  = (const float*)d_in[0];
    const float* pos  = (const float*)d_in[1];
    const float* Wv   = (const float*)d_in[4];
    const float* bv   = (const float*)d_in[5];
    const float* Woff = (const float*)d_in[6];
    const float* boff = (const float*)d_in[7];
    const float* Wa   = (const float*)d_in[8];
    const float* ba   = (const float*)d_in[9];
    const float* Wo   = (const float*)d_in[10];
    const float* bo   = (const float*)d_in[11];
    const float* W1   = (const float*)d_in[12];
    const float* b1   = (const float*)d_in[13];
    const float* W2   = (const float*)d_in[14];
    const float* b2   = (const float*)d_in[15];
    const float* g1   = (const float*)d_in[16];
    const float* be1  = (const float*)d_in[17];
    const float* g2   = (const float*)d_in[18];
    const float* be2  = (const float*)d_in[19];
    float* out = (float*)d_out;

    // Workspace layout. Aliasing (stream-serialized):
    //   tbufB bf16 (11.1MB) aliases srcB (dead after value GEMM)
    //   src2 fp32 (22.3MB)  aliases olg  (dead after sample)
    char* wsp = (char*)d_ws;
    unsigned short* srcB = (unsigned short*)wsp; wsp += NT256 * 2;
    unsigned short* qB   = (unsigned short*)wsp; wsp += NT256 * 2;
    unsigned short* tbufB = srcB;
    __half*         valB = (__half*)wsp;         wsp += NT256 * 2;
    float*          olg  = (float*)wsp;          wsp += (size_t)NTOK * 384 * 4;
    float*          src2 = olg;
    unsigned short* aoB  = (unsigned short*)wsp; wsp += NT256 * 2;
    unsigned short* xB   = (unsigned short*)wsp; wsp += NT256 * 2;
    unsigned short* h    = (unsigned short*)wsp; wsp += (size_t)NTOK * 1024 * 2;
    unsigned short* WvT  = (unsigned short*)wsp; wsp += 256 * 256 * 2;
    unsigned short* WcatT= (unsigned short*)wsp; wsp += 384 * 256 * 2;
    unsigned short* WoT  = (unsigned short*)wsp; wsp += 256 * 256 * 2;
    unsigned short* W1T  = (unsigned short*)wsp; wsp += 1024 * 256 * 2;
    unsigned short* W2T  = (unsigned short*)wsp; wsp += 256 * 1024 * 2;

    const dim3 blk(256);

    // 0. prep + all weight transposes (fused, one launch)
    prep_tr_kernel<<<dim3(5624), blk, 0, stream>>>(
        src, pos, srcB, qB, Wv, Woff, Wa, Wo, W1, W2,
        WvT, WcatT, WoT, W1T, W2T);

    // 1. value = src @ Wv + bv  (fp16 out for sampler) — wide, 170 blocks
    gemm_wide_kernel<256, 256, false, 2><<<dim3(GYR), blk, 0, stream>>>(
        srcB, WvT, bv, bv, 1 << 30, valB);
    // 2. olg = q @ [Woff|Wa] + [boff|ba]  (fp32, N=384, bias split at 256)
    gemm_wide_kernel<256, 384, false, 0><<<dim3(GYR), blk, 0, stream>>>(
        qB, WcatT, boff, ba, 256, olg);
    // 3. fused meta+gather -> attn_out (bf16), batch-per-XCD-pair swizzle
    msda_sample_kernel<<<dim3(NTOK / 8), blk, 0, stream>>>(valB, olg, aoB);
    // 4. src2 = attn_out @ Wo + bo (fp32, overwrites olg)
    gemm_wide_kernel<256, 256, false, 0><<<dim3(GYR), blk, 0, stream>>>(
        aoB, WoT, bo, bo, 1 << 30, src2);
    // 5. xB = bf16(LN(src + src2))
    ln_kernel<false, false, false, true><<<dim3(NTOK / 4), blk, 0, stream>>>(
        src, src2, g1, be1, nullptr, xB);
    // 6. h = relu(xB @ W1 + b1)  (N=1024: keep 128x128 kernel)
    gemm_lds_kernel<256, 8, true, 1><<<dim3(8 * GYP), blk, 0, stream>>>(
        xB, W1T, b1, b1, 1 << 30, h, 1024);
    // 7. t = h @ W2 + b2  (K=1024) — wide, 170 blocks, balanced 1 blk/CU
    gemm_wide_kernel<1024, 256, false, 1><<<dim3(GYR), blk, 0, stream>>>(
        h, W2T, b2, b2, 1 << 30, tbufB);
    // 8. out = LN(xB + t)
    ln_kernel<true, true, true, false><<<dim3(NTOK / 4), blk, 0, stream>>>(
        xB, tbufB, g2, be2, out, nullptr);
}